// Round 13
// baseline (847.934 us; speedup 1.0000x reference)
//
#include <hip/hip_runtime.h>
#include <hip/hip_bf16.h>
#include <hip/hip_cooperative_groups.h>

namespace cg = cooperative_groups;

#define NNODES 50000
#define NEDGES 800000
#define EN 850000   // edges + self loops
#define SCAN_B 196  // ceil(NNODES/256)
#define COOP_B 512

typedef __attribute__((ext_vector_type(8))) short bf16x8;
typedef __attribute__((ext_vector_type(4))) float f32x4;

__device__ __forceinline__ float bf2f(unsigned short u) {
    return __uint_as_float(((unsigned)u) << 16);
}
__device__ __forceinline__ float bflo(unsigned u) { return __uint_as_float(u << 16); }
__device__ __forceinline__ float bfhi(unsigned u) { return __uint_as_float(u & 0xffff0000u); }
__device__ __forceinline__ unsigned short f2bf(float x) {   // RNE
    unsigned u = __float_as_uint(x);
    u += 0x7fffu + ((u >> 16) & 1u);
    return (unsigned short)(u >> 16);
}
__device__ __forceinline__ unsigned pack2bf(float a, float b) {
    return (unsigned)f2bf(a) | ((unsigned)f2bf(b) << 16);
}
__device__ __forceinline__ void acc8(float* acc, uint4 v, float wg) {
    acc[0] += bflo(v.x) * wg; acc[1] += bfhi(v.x) * wg;
    acc[2] += bflo(v.y) * wg; acc[3] += bfhi(v.y) * wg;
    acc[4] += bflo(v.z) * wg; acc[5] += bfhi(v.z) * wg;
    acc[6] += bflo(v.w) * wg; acc[7] += bfhi(v.w) * wg;
}

// ---------------- split helpers ----------------
__device__ __forceinline__ void split_bf(float x, unsigned short& h, unsigned short& l) {
    unsigned u = __float_as_uint(x);
    h = (unsigned short)(u >> 16);
    float r = x - __uint_as_float(u & 0xffff0000u);
    l = (unsigned short)(__float_as_uint(r) >> 16);
}
__device__ __forceinline__ void do_split(const float* W, unsigned short* Wh, unsigned short* Wl,
                                         int i, int K, int N) {
    int n = i / K, k = i - n * K;
    unsigned short h, l;
    split_bf(W[(size_t)k * N + n], h, l);
    Wh[i] = h; Wl[i] = l;
}

// ---------------- shared prep body (one item) ----------------
__device__ __forceinline__ void prep_item(int i, const int* ei, float* deg, const float* x,
                                          unsigned short* xbf,
                                          const float* W1, const float* W2, const float* W3, const float* Wg,
                                          const float* asr, const float* ads,
                                          unsigned short* W1th, unsigned short* W1tl,
                                          unsigned short* W2th, unsigned short* W2tl,
                                          unsigned short* W3th, unsigned short* W3tl,
                                          unsigned short* Wgth, unsigned short* Wgtl,
                                          float* asp, float* adp) {
    atomicAdd(&deg[ei[NEDGES + i]], 1.0f);
    {   // x -> bf16, 8 elems/item
        float4 a = *(const float4*)&x[(size_t)i * 8];
        float4 b = *(const float4*)&x[(size_t)i * 8 + 4];
        uint4 o;
        o.x = pack2bf(a.x, a.y); o.y = pack2bf(a.z, a.w);
        o.z = pack2bf(b.x, b.y); o.w = pack2bf(b.z, b.w);
        *(uint4*)&xbf[(size_t)i * 8] = o;
    }
    if (i < 32768)        do_split(W1, W1th, W1tl, i, 128, 256);
    else if (i < 98304)   do_split(W2, W2th, W2tl, i - 32768, 256, 256);
    else if (i < 131072)  do_split(W3, W3th, W3tl, i - 98304, 256, 128);
    else if (i < 163840)  do_split(Wg, Wgth, Wgtl, i - 131072, 128, 256);
    else if (i < 164864) {   // asp/adp[h][k] = sum_c Wg[k][h*64+c] * a[h][c]
        int i0 = i - 163840;
        int which = i0 >> 9, hh = (i0 >> 7) & 3, k = i0 & 127;
        const float* av = (which ? ads : asr) + hh * 64;
        const float* wg = Wg + (size_t)k * 256 + hh * 64;
        float s = 0.f;
#pragma unroll
        for (int c = 0; c < 64; ++c) s += wg[c] * av[c];
        (which ? adp : asp)[hh * 128 + k] = s;
    }
}

// ---------------- cooperative prologue: zero + prep + scan1 + scan2 + scatter ----------------
__global__ __launch_bounds__(256, 2) void coop_prologue(
    const int* __restrict__ ei, const float* __restrict__ x,
    const float* __restrict__ W1, const float* __restrict__ W2,
    const float* __restrict__ W3, const float* __restrict__ Wg,
    const float* __restrict__ asr, const float* __restrict__ ads,
    float* __restrict__ deg, int* __restrict__ cursor, float* __restrict__ dinv,
    int* __restrict__ rowp, int* __restrict__ bsum, int* __restrict__ bofs,
    uint2* __restrict__ csr, unsigned short* __restrict__ xbf,
    unsigned short* __restrict__ W1th, unsigned short* __restrict__ W1tl,
    unsigned short* __restrict__ W2th, unsigned short* __restrict__ W2tl,
    unsigned short* __restrict__ W3th, unsigned short* __restrict__ W3tl,
    unsigned short* __restrict__ Wgth, unsigned short* __restrict__ Wgtl,
    float* __restrict__ asp, float* __restrict__ adp) {
    __shared__ int sdata[256];
    cg::grid_group grid = cg::this_grid();
    int t = threadIdx.x;
    int tid = blockIdx.x * 256 + t;
    int nthr = gridDim.x * 256;

    // phase 0: zero deg + cursor
    for (int i = tid; i < NNODES; i += nthr) { deg[i] = 0.f; cursor[i] = 0; }
    __threadfence();
    grid.sync();

    // phase 1: prep (800000 items, grid-stride)
    for (int i = tid; i < NEDGES; i += nthr)
        prep_item(i, ei, deg, x, xbf, W1, W2, W3, Wg, asr, ads,
                  W1th, W1tl, W2th, W2tl, W3th, W3tl, Wgth, Wgtl, asp, adp);
    __threadfence();
    grid.sync();

    // phase 2: block-local scan of (deg+1) + dinv, chunk-strided
    for (int c = blockIdx.x; c < SCAN_B; c += gridDim.x) {
        int idx = c * 256 + t;
        float dg = idx < NNODES ? deg[idx] : 0.f;
        if (idx < NNODES) dinv[idx] = rsqrtf(dg + 1.0f);   // +1 = self loop
        int v = idx < NNODES ? (int)dg + 1 : 0;
        sdata[t] = v;
        __syncthreads();
        for (int off = 1; off < 256; off <<= 1) {
            int tmp = t >= off ? sdata[t - off] : 0;
            __syncthreads();
            sdata[t] += tmp;
            __syncthreads();
        }
        if (idx < NNODES) rowp[idx] = sdata[t] - v;   // block-local exclusive
        if (t == 255) bsum[c] = sdata[255];
        __syncthreads();
    }
    __threadfence();
    grid.sync();

    // phase 3: scan of block sums (block 0); rowf(i) = rowp[i] + bofs[i>>8]
    if (blockIdx.x == 0) {
        int v = t < SCAN_B ? bsum[t] : 0;
        sdata[t] = v;
        __syncthreads();
        for (int off = 1; off < 256; off <<= 1) {
            int tmp = t >= off ? sdata[t - off] : 0;
            __syncthreads();
            sdata[t] += tmp;
            __syncthreads();
        }
        if (t < SCAN_B) bofs[t] = sdata[t] - v;
        if (t == SCAN_B - 1) rowp[NNODES] = EN - (sdata[t] - v);
    }
    __threadfence();
    grid.sync();

    // phase 4: scatter edges into CSR {src, weight}
    for (int e = tid; e < EN; e += nthr) {
        int s, d;
        if (e < NEDGES) { s = ei[e]; d = ei[NEDGES + e]; } else { s = e - NEDGES; d = s; }
        int pos = rowp[d] + bofs[d >> 8] + atomicAdd(&cursor[d], 1);
        csr[pos] = make_uint2((unsigned)s, __float_as_uint(dinv[s] * dinv[d]));
    }
}

// ---------------- fallback prologue kernels (proven path) ----------------
__global__ __launch_bounds__(256) void prep_kernel(const int* __restrict__ ei, float* __restrict__ deg,
                                                   const float* __restrict__ x, unsigned short* __restrict__ xbf,
                                                   const float* __restrict__ W1, const float* __restrict__ W2,
                                                   const float* __restrict__ W3, const float* __restrict__ Wg,
                                                   const float* __restrict__ asr, const float* __restrict__ ads,
                                                   unsigned short* __restrict__ W1th, unsigned short* __restrict__ W1tl,
                                                   unsigned short* __restrict__ W2th, unsigned short* __restrict__ W2tl,
                                                   unsigned short* __restrict__ W3th, unsigned short* __restrict__ W3tl,
                                                   unsigned short* __restrict__ Wgth, unsigned short* __restrict__ Wgtl,
                                                   float* __restrict__ asp, float* __restrict__ adp) {
    int idx = blockIdx.x * 256 + threadIdx.x;     // 0..799999
    prep_item(idx, ei, deg, x, xbf, W1, W2, W3, Wg, asr, ads,
              W1th, W1tl, W2th, W2tl, W3th, W3tl, Wgth, Wgtl, asp, adp);
}

__global__ __launch_bounds__(256) void scan_part1(const float* __restrict__ deg, int* __restrict__ row,
                                                  int* __restrict__ bsum, float* __restrict__ dinv) {
    __shared__ int sdata[256];
    int t = threadIdx.x;
    int idx = blockIdx.x * 256 + t;
    float dg = idx < NNODES ? deg[idx] : 0.f;
    if (idx < NNODES) dinv[idx] = rsqrtf(dg + 1.0f);
    int v = idx < NNODES ? (int)dg + 1 : 0;
    sdata[t] = v;
    __syncthreads();
    for (int off = 1; off < 256; off <<= 1) {
        int tmp = t >= off ? sdata[t - off] : 0;
        __syncthreads();
        sdata[t] += tmp;
        __syncthreads();
    }
    if (idx < NNODES) row[idx] = sdata[t] - v;
    if (t == 255) bsum[blockIdx.x] = sdata[255];
}

__global__ __launch_bounds__(256) void scan_part2(int* __restrict__ bsum, int* __restrict__ bofs,
                                                  int* __restrict__ row) {
    __shared__ int sdata[256];
    int t = threadIdx.x;
    int v = t < SCAN_B ? bsum[t] : 0;
    sdata[t] = v;
    __syncthreads();
    for (int off = 1; off < 256; off <<= 1) {
        int tmp = t >= off ? sdata[t - off] : 0;
        __syncthreads();
        sdata[t] += tmp;
        __syncthreads();
    }
    if (t < SCAN_B) bofs[t] = sdata[t] - v;
    if (t == SCAN_B - 1) row[NNODES] = EN - (sdata[t] - v);
}

__global__ __launch_bounds__(256) void scatter_kernel(const int* __restrict__ ei, const int* __restrict__ row,
                                                      const int* __restrict__ bofs,
                                                      int* __restrict__ cursor, const float* __restrict__ dinv,
                                                      uint2* __restrict__ csr) {
    int e = blockIdx.x * blockDim.x + threadIdx.x;
    if (e >= EN) return;
    int s, d;
    if (e < NEDGES) { s = ei[e]; d = ei[NEDGES + e]; } else { s = e - NEDGES; d = s; }
    int pos = row[d] + bofs[d >> 8] + atomicAdd(&cursor[d], 1);
    csr[pos] = make_uint2((unsigned)s, __float_as_uint(dinv[s] * dinv[d]));
}

// ---------------- bf16-input MFMA GEMM: C[M,Nc] = A[M,K] @ W[K,Nc] ----------------
// MODE 0: raw bf16 store; MODE 1: bf16 store of relu(c + bias[col]).
template<int MODE>
__global__ __launch_bounds__(256) void gemm_bf(const unsigned short* __restrict__ A,
                                               const unsigned short* __restrict__ Wth,
                                               const unsigned short* __restrict__ Wtl,
                                               const float* __restrict__ bias,
                                               unsigned short* __restrict__ C, int M, int K, int Nc) {
    __shared__ unsigned short As[128][40];
    __shared__ unsigned short Bh[128][40], Bl[128][40];
    int t = threadIdx.x;
    int row0 = blockIdx.x * 128, col0 = blockIdx.y * 128;
    int lane = t & 63, w = t >> 6;
    int mb = (w >> 1) * 64, nb = (w & 1) * 64;
    int lr = lane & 15, kg = (lane >> 4) * 8;

    f32x4 acc[4][4];
#pragma unroll
    for (int i = 0; i < 4; ++i)
#pragma unroll
        for (int j = 0; j < 4; ++j) acc[i][j] = (f32x4){0.f, 0.f, 0.f, 0.f};

    for (int k0 = 0; k0 < K; k0 += 32) {
#pragma unroll
        for (int it = 0; it < 2; ++it) {
            int q = it * 256 + t;
            int row = q >> 2, seg = (q & 3) * 8;
            int grow = row0 + row;
            uint4 v = make_uint4(0, 0, 0, 0);
            if (grow < M) v = *(const uint4*)&A[(size_t)grow * K + k0 + seg];
            *(uint4*)&As[row][seg] = v;
        }
#pragma unroll
        for (int it = 0; it < 2; ++it) {
            int o = it * 256 + t;
            int n = o >> 2, ko = (o & 3) * 8;
            size_t g = (size_t)(col0 + n) * K + k0 + ko;
            *(uint4*)&Bh[n][ko] = *(const uint4*)&Wth[g];
            *(uint4*)&Bl[n][ko] = *(const uint4*)&Wtl[g];
        }
        __syncthreads();

        bf16x8 a[4], bh[4], bl[4];
#pragma unroll
        for (int mf = 0; mf < 4; ++mf) a[mf] = *(const bf16x8*)&As[mb + mf * 16 + lr][kg];
#pragma unroll
        for (int nf = 0; nf < 4; ++nf) {
            bh[nf] = *(const bf16x8*)&Bh[nb + nf * 16 + lr][kg];
            bl[nf] = *(const bf16x8*)&Bl[nb + nf * 16 + lr][kg];
        }
#pragma unroll
        for (int mf = 0; mf < 4; ++mf)
#pragma unroll
            for (int nf = 0; nf < 4; ++nf) {
                acc[mf][nf] = __builtin_amdgcn_mfma_f32_16x16x32_bf16(a[mf], bh[nf], acc[mf][nf], 0, 0, 0);
                acc[mf][nf] = __builtin_amdgcn_mfma_f32_16x16x32_bf16(a[mf], bl[nf], acc[mf][nf], 0, 0, 0);
            }
        __syncthreads();
    }

#pragma unroll
    for (int nf = 0; nf < 4; ++nf) {
        int col = col0 + nb + nf * 16 + lr;
        float bv = (MODE == 1) ? bias[col] : 0.f;
#pragma unroll
        for (int mf = 0; mf < 4; ++mf) {
#pragma unroll
            for (int r = 0; r < 4; ++r) {
                int row = row0 + mb + mf * 16 + (lane >> 4) * 4 + r;
                if (row < M) {
                    float v = acc[mf][nf][r];
                    if (MODE == 1) v = fmaxf(v + bv, 0.f);
                    C[(size_t)row * Nc + col] = f2bf(v);
                }
            }
        }
    }
}

// ---------------- GCN gather aggregation (bf16, multi-edge, unroll-4) ----------------
// MODE 0: raw sum; MODE 1: relu(sum + b); MODE 2: relu(sum + b) + res(bf16);
// MODE 3: MODE1 + fused attention logits (als/ald from fp32 h3, NC=128 only).
template<int NC, int MODE>
__global__ __launch_bounds__(256) void gcn_agg_bf(const unsigned short* __restrict__ h, const int* __restrict__ row,
                                                  const int* __restrict__ bofs, const uint2* __restrict__ csr,
                                                  const float* __restrict__ b, const unsigned short* __restrict__ res,
                                                  const float* __restrict__ asp, const float* __restrict__ adp,
                                                  float* __restrict__ als, float* __restrict__ ald,
                                                  unsigned short* __restrict__ out) {
    int wid = (int)((blockIdx.x * blockDim.x + threadIdx.x) >> 6);
    if (wid >= NNODES) return;
    int lane = threadIdx.x & 63;
    constexpr int LPE = NC / 8;      // lanes per edge: 32 (NC=256) or 16 (NC=128)
    constexpr int EPI = 64 / LPE;    // edges per iter: 2 or 4
    int sub = lane / LPE, li = lane % LPE;
    int col = li * 8;
    float acc[8];
#pragma unroll
    for (int i = 0; i < 8; ++i) acc[i] = 0.f;
    int j0 = row[wid] + bofs[wid >> 8];
    int j1 = row[wid + 1] + bofs[(wid + 1) >> 8];
    int j = j0 + sub;
    for (; j + 3 * EPI < j1; j += 4 * EPI) {
        uint2 c0 = csr[j], c1 = csr[j + EPI], c2 = csr[j + 2 * EPI], c3 = csr[j + 3 * EPI];
        uint4 v0 = *(const uint4*)&h[(size_t)c0.x * NC + col];
        uint4 v1 = *(const uint4*)&h[(size_t)c1.x * NC + col];
        uint4 v2 = *(const uint4*)&h[(size_t)c2.x * NC + col];
        uint4 v3 = *(const uint4*)&h[(size_t)c3.x * NC + col];
        acc8(acc, v0, __uint_as_float(c0.y));
        acc8(acc, v1, __uint_as_float(c1.y));
        acc8(acc, v2, __uint_as_float(c2.y));
        acc8(acc, v3, __uint_as_float(c3.y));
    }
    for (; j < j1; j += EPI) {
        uint2 c0 = csr[j];
        uint4 v0 = *(const uint4*)&h[(size_t)c0.x * NC + col];
        acc8(acc, v0, __uint_as_float(c0.y));
    }
#pragma unroll
    for (int i = 0; i < 8; ++i) {
        acc[i] += __shfl_xor(acc[i], 32);
        if constexpr (EPI == 4) acc[i] += __shfl_xor(acc[i], 16);
    }
    if (lane < LPE) {
        if constexpr (MODE >= 1) {
#pragma unroll
            for (int i = 0; i < 8; ++i) acc[i] = fmaxf(acc[i] + b[col + i], 0.f);
        }
        if constexpr (MODE == 2) {
            uint4 rv = *(const uint4*)&res[(size_t)wid * NC + col];
            acc8(acc, rv, 1.0f);
        }
        uint4 o;
        o.x = pack2bf(acc[0], acc[1]); o.y = pack2bf(acc[2], acc[3]);
        o.z = pack2bf(acc[4], acc[5]); o.w = pack2bf(acc[6], acc[7]);
        *(uint4*)&out[(size_t)wid * NC + col] = o;
        if constexpr (MODE == 3) {
            float s1[4], s2[4];
#pragma unroll
            for (int hh = 0; hh < 4; ++hh) {
                float t1 = 0.f, t2 = 0.f;
#pragma unroll
                for (int i = 0; i < 8; ++i) {
                    t1 += acc[i] * asp[hh * 128 + col + i];
                    t2 += acc[i] * adp[hh * 128 + col + i];
                }
                s1[hh] = t1; s2[hh] = t2;
            }
#pragma unroll
            for (int off = 1; off <= 8; off <<= 1) {
#pragma unroll
                for (int hh = 0; hh < 4; ++hh) {
                    s1[hh] += __shfl_xor(s1[hh], off);
                    s2[hh] += __shfl_xor(s2[hh], off);
                }
            }
            if (lane == 0) {
                *(float4*)&als[wid * 4] = make_float4(s1[0], s1[1], s1[2], s1[3]);
                *(float4*)&ald[wid * 4] = make_float4(s2[0], s2[1], s2[2], s2[3]);
            }
        }
    }
}

__device__ __forceinline__ float lrelu(float x) { return x < 0.f ? 0.2f * x : x; }

// ---------------- GAT: softmax + hg-space gather, fused bias+relu+block-partial pooling ----------------
// grid must be exactly NNODES/4 = 12500 blocks (all waves own a valid node).
__global__ __launch_bounds__(256) void gat_pool(const unsigned short* __restrict__ hg, const int* __restrict__ row,
                                                const int* __restrict__ bofs, const uint2* __restrict__ csr,
                                                const float* __restrict__ als, const float* __restrict__ ald,
                                                const float* __restrict__ bg, float* __restrict__ ppart) {
    __shared__ float alds[4][64][4];   // [wave][edge slot][head] normalized alpha
    __shared__ float srows[4][256];    // per-wave output row (fp32)
    int wid = (int)((blockIdx.x * blockDim.x + threadIdx.x) >> 6);
    int wv = threadIdx.x >> 6;
    int lane = threadIdx.x & 63;
    int j0 = row[wid] + bofs[wid >> 8];
    int j1 = row[wid + 1] + bofs[(wid + 1) >> 8];
    int deg = j1 - j0;
    float4 ad = *(const float4*)&ald[wid * 4];
    int sub = lane >> 5, li = lane & 31;
    int h = li >> 3;                 // head for this lane's 8-col slice
    int col = li * 8;
    float acc[8];
#pragma unroll
    for (int i = 0; i < 8; ++i) acc[i] = 0.f;

    if (deg <= 64) {
        int sreg = 0;
        float e0 = -1e30f, e1 = -1e30f, e2 = -1e30f, e3 = -1e30f;
        if (lane < deg) {
            sreg = (int)csr[j0 + lane].x;
            float4 as4 = *(const float4*)&als[sreg * 4];
            e0 = lrelu(as4.x + ad.x); e1 = lrelu(as4.y + ad.y);
            e2 = lrelu(as4.z + ad.z); e3 = lrelu(as4.w + ad.w);
        }
        float m0 = e0, m1 = e1, m2 = e2, m3 = e3;
#pragma unroll
        for (int off = 32; off >= 1; off >>= 1) {
            m0 = fmaxf(m0, __shfl_xor(m0, off));
            m1 = fmaxf(m1, __shfl_xor(m1, off));
            m2 = fmaxf(m2, __shfl_xor(m2, off));
            m3 = fmaxf(m3, __shfl_xor(m3, off));
        }
        float x0 = __expf(e0 - m0), x1 = __expf(e1 - m1);
        float x2 = __expf(e2 - m2), x3 = __expf(e3 - m3);
        float d0 = x0, d1 = x1, d2 = x2, d3 = x3;
#pragma unroll
        for (int off = 32; off >= 1; off >>= 1) {
            d0 += __shfl_xor(d0, off);
            d1 += __shfl_xor(d1, off);
            d2 += __shfl_xor(d2, off);
            d3 += __shfl_xor(d3, off);
        }
        *(float4*)&alds[wv][lane][0] = make_float4(x0 / d0, x1 / d1, x2 / d2, x3 / d3);
        int k = sub;
        for (; k + 6 < deg; k += 8) {
            int s0 = __shfl(sreg, k),     int1 = __shfl(sreg, k + 2);
            int s2 = __shfl(sreg, k + 4), s3 = __shfl(sreg, k + 6);
            float a0 = alds[wv][k][h],     a1 = alds[wv][k + 2][h];
            float a2 = alds[wv][k + 4][h], a3 = alds[wv][k + 6][h];
            uint4 v0 = *(const uint4*)&hg[(size_t)s0 * 256 + col];
            uint4 v1 = *(const uint4*)&hg[(size_t)int1 * 256 + col];
            uint4 v2 = *(const uint4*)&hg[(size_t)s2 * 256 + col];
            uint4 v3 = *(const uint4*)&hg[(size_t)s3 * 256 + col];
            acc8(acc, v0, a0); acc8(acc, v1, a1);
            acc8(acc, v2, a2); acc8(acc, v3, a3);
        }
        for (; k < deg; k += 2) {
            int s0 = __shfl(sreg, k);
            float a0 = alds[wv][k][h];
            uint4 v0 = *(const uint4*)&hg[(size_t)s0 * 256 + col];
            acc8(acc, v0, a0);
        }
    } else {
        float m0 = -1e30f, m1 = -1e30f, m2 = -1e30f, m3 = -1e30f;
        float d0 = 0.f, d1 = 0.f, d2 = 0.f, d3 = 0.f;
        for (int j = j0 + lane; j < j1; j += 64) {
            int s = (int)csr[j].x;
            float4 as4 = *(const float4*)&als[s * 4];
            m0 = fmaxf(m0, lrelu(as4.x + ad.x));
            m1 = fmaxf(m1, lrelu(as4.y + ad.y));
            m2 = fmaxf(m2, lrelu(as4.z + ad.z));
            m3 = fmaxf(m3, lrelu(as4.w + ad.w));
        }
#pragma unroll
        for (int off = 32; off >= 1; off >>= 1) {
            m0 = fmaxf(m0, __shfl_xor(m0, off));
            m1 = fmaxf(m1, __shfl_xor(m1, off));
            m2 = fmaxf(m2, __shfl_xor(m2, off));
            m3 = fmaxf(m3, __shfl_xor(m3, off));
        }
        for (int j = j0 + lane; j < j1; j += 64) {
            int s = (int)csr[j].x;
            float4 as4 = *(const float4*)&als[s * 4];
            d0 += __expf(lrelu(as4.x + ad.x) - m0);
            d1 += __expf(lrelu(as4.y + ad.y) - m1);
            d2 += __expf(lrelu(as4.z + ad.z) - m2);
            d3 += __expf(lrelu(as4.w + ad.w) - m3);
        }
#pragma unroll
        for (int off = 32; off >= 1; off >>= 1) {
            d0 += __shfl_xor(d0, off);
            d1 += __shfl_xor(d1, off);
            d2 += __shfl_xor(d2, off);
            d3 += __shfl_xor(d3, off);
        }
        float mh   = h == 0 ? m0 : h == 1 ? m1 : h == 2 ? m2 : m3;
        float invh = 1.f / (h == 0 ? d0 : h == 1 ? d1 : h == 2 ? d2 : d3);
        float adh  = h == 0 ? ad.x : h == 1 ? ad.y : h == 2 ? ad.z : ad.w;
        for (int j = j0 + sub; j < j1; j += 2) {
            uint2 c0 = csr[j];
            float a0 = __expf(lrelu(als[c0.x * 4 + h] + adh) - mh) * invh;
            uint4 v0 = *(const uint4*)&hg[(size_t)c0.x * 256 + col];
            acc8(acc, v0, a0);
        }
    }

    // epilogue: fold sub-halves, bias+relu into LDS, block-level column partial -> ppart
#pragma unroll
    for (int i = 0; i < 8; ++i) acc[i] += __shfl_xor(acc[i], 32);
    if (lane < 32) {
#pragma unroll
        for (int i = 0; i < 8; ++i) srows[wv][col + i] = fmaxf(acc[i] + bg[col + i], 0.f);
    }
    __syncthreads();
    int t = threadIdx.x;
    ppart[(size_t)blockIdx.x * 256 + t] = srows[0][t] + srows[1][t] + srows[2][t] + srows[3][t];
}

// ---------------- reduce 12500 block partials -> 196 partials ----------------
__global__ __launch_bounds__(256) void reduce_kernel(const float* __restrict__ ppart, float* __restrict__ p2) {
    int t = threadIdx.x;
    int r0 = blockIdx.x * 64;
    int r1 = r0 + 64 < 12500 ? r0 + 64 : 12500;
    float s = 0.f;
    for (int r = r0; r < r1; ++r) s += ppart[(size_t)r * 256 + t];
    p2[blockIdx.x * 256 + t] = s;
}

__global__ __launch_bounds__(256) void mlp_kernel(const float* __restrict__ p2,
                                                  const float* __restrict__ Wc1, const float* __restrict__ bc1,
                                                  const float* __restrict__ Wc2, const float* __restrict__ bc2,
                                                  const float* __restrict__ Wc3, const float* __restrict__ bc3,
                                                  float* __restrict__ out) {
    __shared__ float p[256], z1[128], z2[64];
    int t = threadIdx.x;
    float s0 = 0.f;
    for (int b = 0; b < SCAN_B; ++b) s0 += p2[b * 256 + t];
    p[t] = s0 * (1.0f / NNODES);
    __syncthreads();
    if (t < 128) {
        float s = bc1[t];
        for (int k = 0; k < 256; ++k) s += p[k] * Wc1[k * 128 + t];
        z1[t] = fmaxf(s, 0.f);
    }
    __syncthreads();
    if (t < 64) {
        float s = bc2[t];
        for (int k = 0; k < 128; ++k) s += z1[k] * Wc2[k * 64 + t];
        z2[t] = fmaxf(s, 0.f);
    }
    __syncthreads();
    if (t < 8) {
        float s = bc3[t];
        for (int k = 0; k < 64; ++k) s += z2[k] * Wc3[k * 8 + t];
        out[t] = s;
    }
}

extern "C" void kernel_launch(void* const* d_in, const int* in_sizes, int n_in,
                              void* d_out, int out_size, void* d_ws, size_t ws_size,
                              hipStream_t stream) {
    const float* x   = (const float*)d_in[0];
    const int*   ei  = (const int*)d_in[1];
    const float* W1  = (const float*)d_in[2];  const float* b1  = (const float*)d_in[3];
    const float* W2  = (const float*)d_in[4];  const float* b2  = (const float*)d_in[5];
    const float* W3  = (const float*)d_in[6];  const float* b3  = (const float*)d_in[7];
    const float* Wg  = (const float*)d_in[8];
    const float* asr = (const float*)d_in[9];  const float* ads = (const float*)d_in[10];
    const float* bg  = (const float*)d_in[11];
    const float* Wc1 = (const float*)d_in[12]; const float* bc1 = (const float*)d_in[13];
    const float* Wc2 = (const float*)d_in[14]; const float* bc2 = (const float*)d_in[15];
    const float* Wc3 = (const float*)d_in[16]; const float* bc3 = (const float*)d_in[17];
    float* out = (float*)d_out;

    char* w = (char*)d_ws;
    float* deg    = (float*)w; w += (size_t)NNODES * 4;          // deg+cursor adjacent: one memset
    int*   cursor = (int*)w;   w += (size_t)NNODES * 4;
    float* dinv   = (float*)w; w += (size_t)NNODES * 4;
    int*   rowp   = (int*)w;   w += 200016;                      // (NNODES+1)*4 padded
    int*   bsum   = (int*)w;   w += 256 * 4;
    int*   bofs   = (int*)w;   w += 256 * 4;
    uint2* csr    = (uint2*)w; w += (size_t)EN * 8;
    float* als    = (float*)w; w += (size_t)NNODES * 4 * 4;
    float* ald    = (float*)w; w += (size_t)NNODES * 4 * 4;
    float* ppart  = (float*)w; w += (size_t)12500 * 256 * 4;
    float* p2     = (float*)w; w += (size_t)SCAN_B * 256 * 4;
    float* asp    = (float*)w; w += 4 * 128 * 4;
    float* adp    = (float*)w; w += 4 * 128 * 4;
    unsigned short* W1th = (unsigned short*)w; w += 128 * 256 * 2;
    unsigned short* W1tl = (unsigned short*)w; w += 128 * 256 * 2;
    unsigned short* W2th = (unsigned short*)w; w += 256 * 256 * 2;
    unsigned short* W2tl = (unsigned short*)w; w += 256 * 256 * 2;
    unsigned short* W3th = (unsigned short*)w; w += 256 * 128 * 2;
    unsigned short* W3tl = (unsigned short*)w; w += 256 * 128 * 2;
    unsigned short* Wgth = (unsigned short*)w; w += 128 * 256 * 2;
    unsigned short* Wgtl = (unsigned short*)w; w += 128 * 256 * 2;
    unsigned short* U1 = (unsigned short*)w; w += (size_t)NNODES * 256 * 2;
    unsigned short* U2 = (unsigned short*)w; w += (size_t)NNODES * 256 * 2;
    unsigned short* U3 = (unsigned short*)w; w += (size_t)NNODES * 256 * 2;
    unsigned short* U4 = (unsigned short*)w; w += (size_t)NNODES * 256 * 2;

    // prologue: try one cooperative kernel; fall back to proven 5-dispatch path on failure.
    void* cargs[] = {(void*)&ei, (void*)&x, (void*)&W1, (void*)&W2, (void*)&W3, (void*)&Wg,
                     (void*)&asr, (void*)&ads,
                     (void*)&deg, (void*)&cursor, (void*)&dinv, (void*)&rowp, (void*)&bsum, (void*)&bofs,
                     (void*)&csr, (void*)&U1,
                     (void*)&W1th, (void*)&W1tl, (void*)&W2th, (void*)&W2tl,
                     (void*)&W3th, (void*)&W3tl, (void*)&Wgth, (void*)&Wgtl,
                     (void*)&asp, (void*)&adp};
    hipError_t cerr = hipLaunchCooperativeKernel((const void*)coop_prologue, dim3(COOP_B), dim3(256),
                                                 cargs, 0, stream);
    if (cerr != hipSuccess) {
        hipMemsetAsync(deg, 0, (size_t)NNODES * 8, stream);
        prep_kernel<<<3125, 256, 0, stream>>>(ei, deg, x, U1, W1, W2, W3, Wg, asr, ads,
                                              W1th, W1tl, W2th, W2tl, W3th, W3tl, Wgth, Wgtl, asp, adp);
        scan_part1<<<SCAN_B, 256, 0, stream>>>(deg, rowp, bsum, dinv);
        scan_part2<<<1, 256, 0, stream>>>(bsum, bofs, rowp);
        scatter_kernel<<<(EN + 255) / 256, 256, 0, stream>>>(ei, rowp, bofs, cursor, dinv, csr);
    }

    dim3 gA((NNODES + 127) / 128, 2);   // Nc = 256
    dim3 gB((NNODES + 127) / 128, 1);   // Nc = 128
    int aggBlocks = (NNODES * 64 + 255) / 256;   // 12500

    // GCN 1 (reordered): aggX = agg(xbf) [N,128] -> U2; h1 = relu(aggX@W1 + b1) -> U3
    gcn_agg_bf<128, 0><<<aggBlocks, 256, 0, stream>>>(U1, rowp, bofs, csr, nullptr, nullptr,
                                                      nullptr, nullptr, nullptr, nullptr, U2);
    gemm_bf<1><<<gA, 256, 0, stream>>>(U2, W1th, W1tl, b1, U3, NNODES, 128, 256);

    // GCN 2: t2 = h1@W2 -> U1; h2 = relu(agg(t2) + b2) + h1 -> U2
    gemm_bf<0><<<gA, 256, 0, stream>>>(U3, W2th, W2tl, nullptr, U1, NNODES, 256, 256);
    gcn_agg_bf<256, 2><<<aggBlocks, 256, 0, stream>>>(U1, rowp, bofs, csr, b2, U3,
                                                      nullptr, nullptr, nullptr, nullptr, U2);

    // GCN 3: t3 = h2@W3 -> U4 [N,128]; h3 = relu(agg(t3) + b3) -> U1 + fused logits
    gemm_bf<0><<<gB, 256, 0, stream>>>(U2, W3th, W3tl, nullptr, U4, NNODES, 256, 128);
    gcn_agg_bf<128, 3><<<aggBlocks, 256, 0, stream>>>(U4, rowp, bofs, csr, b3, nullptr,
                                                      asp, adp, als, ald, U1);

    // GAT: hg = h3@Wg -> U2 [N,256]; softmax + gather + bias/relu + partial pool -> ppart
    gemm_bf<0><<<gA, 256, 0, stream>>>(U1, Wgth, Wgtl, nullptr, U2, NNODES, 128, 256);
    gat_pool<<<aggBlocks, 256, 0, stream>>>(U2, rowp, bofs, csr, als, ald, bg, ppart);

    // mean pool + MLP
    reduce_kernel<<<SCAN_B, 256, 0, stream>>>(ppart, p2);
    mlp_kernel<<<1, 256, 0, stream>>>(p2, Wc1, bc1, Wc2, bc2, Wc3, bc3, out);
}

// Round 14
// 496.323 us; speedup vs baseline: 1.7084x; 1.7084x over previous
//
#include <hip/hip_runtime.h>
#include <hip/hip_bf16.h>

#define NNODES 50000
#define NEDGES 800000
#define EN 850000   // edges + self loops
#define SCAN_B 196  // ceil(NNODES/256)

typedef __attribute__((ext_vector_type(8))) short bf16x8;
typedef __attribute__((ext_vector_type(4))) float f32x4;

__device__ __forceinline__ float bf2f(unsigned short u) {
    return __uint_as_float(((unsigned)u) << 16);
}
__device__ __forceinline__ float bflo(unsigned u) { return __uint_as_float(u << 16); }
__device__ __forceinline__ float bfhi(unsigned u) { return __uint_as_float(u & 0xffff0000u); }
__device__ __forceinline__ unsigned short f2bf(float x) {   // RNE
    unsigned u = __float_as_uint(x);
    u += 0x7fffu + ((u >> 16) & 1u);
    return (unsigned short)(u >> 16);
}
__device__ __forceinline__ unsigned pack2bf(float a, float b) {
    return (unsigned)f2bf(a) | ((unsigned)f2bf(b) << 16);
}
__device__ __forceinline__ void acc8(float* acc, uint4 v, float wg) {
    acc[0] += bflo(v.x) * wg; acc[1] += bfhi(v.x) * wg;
    acc[2] += bflo(v.y) * wg; acc[3] += bfhi(v.y) * wg;
    acc[4] += bflo(v.z) * wg; acc[5] += bfhi(v.z) * wg;
    acc[6] += bflo(v.w) * wg; acc[7] += bfhi(v.w) * wg;
}

// ---------------- split helpers ----------------
__device__ __forceinline__ void split_bf(float x, unsigned short& h, unsigned short& l) {
    unsigned u = __float_as_uint(x);
    h = (unsigned short)(u >> 16);
    float r = x - __uint_as_float(u & 0xffff0000u);
    l = (unsigned short)(__float_as_uint(r) >> 16);
}
__device__ __forceinline__ void do_split(const float* W, unsigned short* Wh, unsigned short* Wl,
                                         int i, int K, int N) {
    int n = i / K, k = i - n * K;
    unsigned short h, l;
    split_bf(W[(size_t)k * N + n], h, l);
    Wh[i] = h; Wl[i] = l;
}

// ---------------- fused prep: deg atomics + x->bf16 + weight splits + attn projections ----------------
__global__ __launch_bounds__(256) void prep_kernel(const int* __restrict__ ei, float* __restrict__ deg,
                                                   const float* __restrict__ x, unsigned short* __restrict__ xbf,
                                                   const float* __restrict__ W1, const float* __restrict__ W2,
                                                   const float* __restrict__ W3, const float* __restrict__ Wg,
                                                   const float* __restrict__ asr, const float* __restrict__ ads,
                                                   unsigned short* __restrict__ W1th, unsigned short* __restrict__ W1tl,
                                                   unsigned short* __restrict__ W2th, unsigned short* __restrict__ W2tl,
                                                   unsigned short* __restrict__ W3th, unsigned short* __restrict__ W3tl,
                                                   unsigned short* __restrict__ Wgth, unsigned short* __restrict__ Wgtl,
                                                   float* __restrict__ asp, float* __restrict__ adp) {
    int idx = blockIdx.x * 256 + threadIdx.x;     // 0..799999
    atomicAdd(&deg[ei[NEDGES + idx]], 1.0f);      // idx < NEDGES always
    {   // x -> bf16, 8 elems/thread
        float4 a = *(const float4*)&x[(size_t)idx * 8];
        float4 b = *(const float4*)&x[(size_t)idx * 8 + 4];
        uint4 o;
        o.x = pack2bf(a.x, a.y); o.y = pack2bf(a.z, a.w);
        o.z = pack2bf(b.x, b.y); o.w = pack2bf(b.z, b.w);
        *(uint4*)&xbf[(size_t)idx * 8] = o;
    }
    if (idx < 32768)        do_split(W1, W1th, W1tl, idx, 128, 256);
    else if (idx < 98304)   do_split(W2, W2th, W2tl, idx - 32768, 256, 256);
    else if (idx < 131072)  do_split(W3, W3th, W3tl, idx - 98304, 256, 128);
    else if (idx < 163840)  do_split(Wg, Wgth, Wgtl, idx - 131072, 128, 256);
    else if (idx < 164864) {   // asp/adp[h][k] = sum_c Wg[k][h*64+c] * a[h][c]
        int i0 = idx - 163840;       // [0,1024)
        int which = i0 >> 9;         // 0: src, 1: dst
        int h = (i0 >> 7) & 3;
        int k = i0 & 127;
        const float* av = (which ? ads : asr) + h * 64;
        const float* wg = Wg + (size_t)k * 256 + h * 64;
        float s = 0.f;
#pragma unroll
        for (int c = 0; c < 64; ++c) s += wg[c] * av[c];
        (which ? adp : asp)[h * 128 + k] = s;
    }
}

// ---------------- hierarchical exclusive scan of (deg[i]+1), fused dinv ----------------
__global__ __launch_bounds__(256) void scan_part1(const float* __restrict__ deg, int* __restrict__ row,
                                                  int* __restrict__ bsum, float* __restrict__ dinv) {
    __shared__ int sdata[256];
    int t = threadIdx.x;
    int idx = blockIdx.x * 256 + t;
    float dg = idx < NNODES ? deg[idx] : 0.f;
    if (idx < NNODES) dinv[idx] = rsqrtf(dg + 1.0f);   // +1 = self loop
    int v = idx < NNODES ? (int)dg + 1 : 0;
    sdata[t] = v;
    __syncthreads();
    for (int off = 1; off < 256; off <<= 1) {
        int tmp = t >= off ? sdata[t - off] : 0;
        __syncthreads();
        sdata[t] += tmp;
        __syncthreads();
    }
    if (idx < NNODES) row[idx] = sdata[t] - v;   // block-local exclusive
    if (t == 255) bsum[blockIdx.x] = sdata[255];
}

// consumers compute rowf(i) = row[i] + bofs[i>>8]; part2 patches row[NNODES]
__global__ __launch_bounds__(256) void scan_part2(int* __restrict__ bsum, int* __restrict__ bofs,
                                                  int* __restrict__ row) {
    __shared__ int sdata[256];
    int t = threadIdx.x;
    int v = t < SCAN_B ? bsum[t] : 0;
    sdata[t] = v;
    __syncthreads();
    for (int off = 1; off < 256; off <<= 1) {
        int tmp = t >= off ? sdata[t - off] : 0;
        __syncthreads();
        sdata[t] += tmp;
        __syncthreads();
    }
    if (t < SCAN_B) bofs[t] = sdata[t] - v;
    if (t == SCAN_B - 1) row[NNODES] = EN - (sdata[t] - v);   // rowf(NNODES) == EN
}

// csr entry: {src, weight-bits} interleaved
__global__ __launch_bounds__(256) void scatter_kernel(const int* __restrict__ ei, const int* __restrict__ row,
                                                      const int* __restrict__ bofs,
                                                      int* __restrict__ cursor, const float* __restrict__ dinv,
                                                      uint2* __restrict__ csr) {
    int e = blockIdx.x * blockDim.x + threadIdx.x;
    if (e >= EN) return;
    int s, d;
    if (e < NEDGES) { s = ei[e]; d = ei[NEDGES + e]; } else { s = e - NEDGES; d = s; }
    int pos = row[d] + bofs[d >> 8] + atomicAdd(&cursor[d], 1);
    csr[pos] = make_uint2((unsigned)s, __float_as_uint(dinv[s] * dinv[d]));
}

// ---------------- bf16-input MFMA GEMM: C[M,Nc] = A[M,K] @ W[K,Nc] ----------------
// MODE 0: raw bf16 store; MODE 1: bf16 store of relu(c + bias[col]).
template<int MODE>
__global__ __launch_bounds__(256) void gemm_bf(const unsigned short* __restrict__ A,
                                               const unsigned short* __restrict__ Wth,
                                               const unsigned short* __restrict__ Wtl,
                                               const float* __restrict__ bias,
                                               unsigned short* __restrict__ C, int M, int K, int Nc) {
    __shared__ unsigned short As[128][40];
    __shared__ unsigned short Bh[128][40], Bl[128][40];
    int t = threadIdx.x;
    int row0 = blockIdx.x * 128, col0 = blockIdx.y * 128;
    int lane = t & 63, w = t >> 6;
    int mb = (w >> 1) * 64, nb = (w & 1) * 64;
    int lr = lane & 15, kg = (lane >> 4) * 8;

    f32x4 acc[4][4];
#pragma unroll
    for (int i = 0; i < 4; ++i)
#pragma unroll
        for (int j = 0; j < 4; ++j) acc[i][j] = (f32x4){0.f, 0.f, 0.f, 0.f};

    for (int k0 = 0; k0 < K; k0 += 32) {
#pragma unroll
        for (int it = 0; it < 2; ++it) {
            int q = it * 256 + t;
            int row = q >> 2, seg = (q & 3) * 8;
            int grow = row0 + row;
            uint4 v = make_uint4(0, 0, 0, 0);
            if (grow < M) v = *(const uint4*)&A[(size_t)grow * K + k0 + seg];
            *(uint4*)&As[row][seg] = v;
        }
#pragma unroll
        for (int it = 0; it < 2; ++it) {
            int o = it * 256 + t;
            int n = o >> 2, ko = (o & 3) * 8;
            size_t g = (size_t)(col0 + n) * K + k0 + ko;
            *(uint4*)&Bh[n][ko] = *(const uint4*)&Wth[g];
            *(uint4*)&Bl[n][ko] = *(const uint4*)&Wtl[g];
        }
        __syncthreads();

        bf16x8 a[4], bh[4], bl[4];
#pragma unroll
        for (int mf = 0; mf < 4; ++mf) a[mf] = *(const bf16x8*)&As[mb + mf * 16 + lr][kg];
#pragma unroll
        for (int nf = 0; nf < 4; ++nf) {
            bh[nf] = *(const bf16x8*)&Bh[nb + nf * 16 + lr][kg];
            bl[nf] = *(const bf16x8*)&Bl[nb + nf * 16 + lr][kg];
        }
#pragma unroll
        for (int mf = 0; mf < 4; ++mf)
#pragma unroll
            for (int nf = 0; nf < 4; ++nf) {
                acc[mf][nf] = __builtin_amdgcn_mfma_f32_16x16x32_bf16(a[mf], bh[nf], acc[mf][nf], 0, 0, 0);
                acc[mf][nf] = __builtin_amdgcn_mfma_f32_16x16x32_bf16(a[mf], bl[nf], acc[mf][nf], 0, 0, 0);
            }
        __syncthreads();
    }

#pragma unroll
    for (int nf = 0; nf < 4; ++nf) {
        int col = col0 + nb + nf * 16 + lr;
        float bv = (MODE == 1) ? bias[col] : 0.f;
#pragma unroll
        for (int mf = 0; mf < 4; ++mf) {
#pragma unroll
            for (int r = 0; r < 4; ++r) {
                int row = row0 + mb + mf * 16 + (lane >> 4) * 4 + r;
                if (row < M) {
                    float v = acc[mf][nf][r];
                    if (MODE == 1) v = fmaxf(v + bv, 0.f);
                    C[(size_t)row * Nc + col] = f2bf(v);
                }
            }
        }
    }
}

// ---------------- GCN gather aggregation (bf16, multi-edge, unroll-4) ----------------
// MODE 0: raw sum; MODE 1: relu(sum + b); MODE 2: relu(sum + b) + res(bf16);
// MODE 3: MODE1 + fused attention logits (als/ald from fp32 h3, NC=128 only).
template<int NC, int MODE>
__global__ __launch_bounds__(256) void gcn_agg_bf(const unsigned short* __restrict__ h, const int* __restrict__ row,
                                                  const int* __restrict__ bofs, const uint2* __restrict__ csr,
                                                  const float* __restrict__ b, const unsigned short* __restrict__ res,
                                                  const float* __restrict__ asp, const float* __restrict__ adp,
                                                  float* __restrict__ als, float* __restrict__ ald,
                                                  unsigned short* __restrict__ out) {
    int wid = (int)((blockIdx.x * blockDim.x + threadIdx.x) >> 6);
    if (wid >= NNODES) return;
    int lane = threadIdx.x & 63;
    constexpr int LPE = NC / 8;      // lanes per edge: 32 (NC=256) or 16 (NC=128)
    constexpr int EPI = 64 / LPE;    // edges per iter: 2 or 4
    int sub = lane / LPE, li = lane % LPE;
    int col = li * 8;
    float acc[8];
#pragma unroll
    for (int i = 0; i < 8; ++i) acc[i] = 0.f;
    int j0 = row[wid] + bofs[wid >> 8];
    int j1 = row[wid + 1] + bofs[(wid + 1) >> 8];
    int j = j0 + sub;
    for (; j + 3 * EPI < j1; j += 4 * EPI) {
        uint2 c0 = csr[j], c1 = csr[j + EPI], c2 = csr[j + 2 * EPI], c3 = csr[j + 3 * EPI];
        uint4 v0 = *(const uint4*)&h[(size_t)c0.x * NC + col];
        uint4 v1 = *(const uint4*)&h[(size_t)c1.x * NC + col];
        uint4 v2 = *(const uint4*)&h[(size_t)c2.x * NC + col];
        uint4 v3 = *(const uint4*)&h[(size_t)c3.x * NC + col];
        acc8(acc, v0, __uint_as_float(c0.y));
        acc8(acc, v1, __uint_as_float(c1.y));
        acc8(acc, v2, __uint_as_float(c2.y));
        acc8(acc, v3, __uint_as_float(c3.y));
    }
    for (; j < j1; j += EPI) {
        uint2 c0 = csr[j];
        uint4 v0 = *(const uint4*)&h[(size_t)c0.x * NC + col];
        acc8(acc, v0, __uint_as_float(c0.y));
    }
#pragma unroll
    for (int i = 0; i < 8; ++i) {
        acc[i] += __shfl_xor(acc[i], 32);
        if constexpr (EPI == 4) acc[i] += __shfl_xor(acc[i], 16);
    }
    if (lane < LPE) {
        if constexpr (MODE >= 1) {
#pragma unroll
            for (int i = 0; i < 8; ++i) acc[i] = fmaxf(acc[i] + b[col + i], 0.f);
        }
        if constexpr (MODE == 2) {
            uint4 rv = *(const uint4*)&res[(size_t)wid * NC + col];
            acc8(acc, rv, 1.0f);
        }
        uint4 o;
        o.x = pack2bf(acc[0], acc[1]); o.y = pack2bf(acc[2], acc[3]);
        o.z = pack2bf(acc[4], acc[5]); o.w = pack2bf(acc[6], acc[7]);
        *(uint4*)&out[(size_t)wid * NC + col] = o;
        if constexpr (MODE == 3) {
            float s1[4], s2[4];
#pragma unroll
            for (int hh = 0; hh < 4; ++hh) {
                float t1 = 0.f, t2 = 0.f;
#pragma unroll
                for (int i = 0; i < 8; ++i) {
                    t1 += acc[i] * asp[hh * 128 + col + i];
                    t2 += acc[i] * adp[hh * 128 + col + i];
                }
                s1[hh] = t1; s2[hh] = t2;
            }
#pragma unroll
            for (int off = 1; off <= 8; off <<= 1) {
#pragma unroll
                for (int hh = 0; hh < 4; ++hh) {
                    s1[hh] += __shfl_xor(s1[hh], off);
                    s2[hh] += __shfl_xor(s2[hh], off);
                }
            }
            if (lane == 0) {
                *(float4*)&als[wid * 4] = make_float4(s1[0], s1[1], s1[2], s1[3]);
                *(float4*)&ald[wid * 4] = make_float4(s2[0], s2[1], s2[2], s2[3]);
            }
        }
    }
}

__device__ __forceinline__ float lrelu(float x) { return x < 0.f ? 0.2f * x : x; }

// ---------------- GAT: softmax + hg-space gather, fused bias+relu+block-partial pooling ----------------
// grid must be exactly NNODES/4 = 12500 blocks (all waves own a valid node).
__global__ __launch_bounds__(256) void gat_pool(const unsigned short* __restrict__ hg, const int* __restrict__ row,
                                                const int* __restrict__ bofs, const uint2* __restrict__ csr,
                                                const float* __restrict__ als, const float* __restrict__ ald,
                                                const float* __restrict__ bg, float* __restrict__ ppart) {
    __shared__ float alds[4][64][4];   // [wave][edge slot][head] normalized alpha
    __shared__ float srows[4][256];    // per-wave output row (fp32)
    int wid = (int)((blockIdx.x * blockDim.x + threadIdx.x) >> 6);
    int wv = threadIdx.x >> 6;
    int lane = threadIdx.x & 63;
    int j0 = row[wid] + bofs[wid >> 8];
    int j1 = row[wid + 1] + bofs[(wid + 1) >> 8];
    int deg = j1 - j0;
    float4 ad = *(const float4*)&ald[wid * 4];
    int sub = lane >> 5, li = lane & 31;
    int h = li >> 3;                 // head for this lane's 8-col slice
    int col = li * 8;
    float acc[8];
#pragma unroll
    for (int i = 0; i < 8; ++i) acc[i] = 0.f;

    if (deg <= 64) {
        int sreg = 0;
        float e0 = -1e30f, e1 = -1e30f, e2 = -1e30f, e3 = -1e30f;
        if (lane < deg) {
            sreg = (int)csr[j0 + lane].x;
            float4 as4 = *(const float4*)&als[sreg * 4];
            e0 = lrelu(as4.x + ad.x); e1 = lrelu(as4.y + ad.y);
            e2 = lrelu(as4.z + ad.z); e3 = lrelu(as4.w + ad.w);
        }
        float m0 = e0, m1 = e1, m2 = e2, m3 = e3;
#pragma unroll
        for (int off = 32; off >= 1; off >>= 1) {
            m0 = fmaxf(m0, __shfl_xor(m0, off));
            m1 = fmaxf(m1, __shfl_xor(m1, off));
            m2 = fmaxf(m2, __shfl_xor(m2, off));
            m3 = fmaxf(m3, __shfl_xor(m3, off));
        }
        float x0 = __expf(e0 - m0), x1 = __expf(e1 - m1);
        float x2 = __expf(e2 - m2), x3 = __expf(e3 - m3);
        float d0 = x0, d1 = x1, d2 = x2, d3 = x3;
#pragma unroll
        for (int off = 32; off >= 1; off >>= 1) {
            d0 += __shfl_xor(d0, off);
            d1 += __shfl_xor(d1, off);
            d2 += __shfl_xor(d2, off);
            d3 += __shfl_xor(d3, off);
        }
        *(float4*)&alds[wv][lane][0] = make_float4(x0 / d0, x1 / d1, x2 / d2, x3 / d3);
        int k = sub;
        for (; k + 6 < deg; k += 8) {
            int s0 = __shfl(sreg, k),     s1 = __shfl(sreg, k + 2);
            int s2 = __shfl(sreg, k + 4), s3 = __shfl(sreg, k + 6);
            float a0 = alds[wv][k][h],     a1 = alds[wv][k + 2][h];
            float a2 = alds[wv][k + 4][h], a3 = alds[wv][k + 6][h];
            uint4 v0 = *(const uint4*)&hg[(size_t)s0 * 256 + col];
            uint4 v1 = *(const uint4*)&hg[(size_t)s1 * 256 + col];
            uint4 v2 = *(const uint4*)&hg[(size_t)s2 * 256 + col];
            uint4 v3 = *(const uint4*)&hg[(size_t)s3 * 256 + col];
            acc8(acc, v0, a0); acc8(acc, v1, a1);
            acc8(acc, v2, a2); acc8(acc, v3, a3);
        }
        for (; k < deg; k += 2) {
            int s0 = __shfl(sreg, k);
            float a0 = alds[wv][k][h];
            uint4 v0 = *(const uint4*)&hg[(size_t)s0 * 256 + col];
            acc8(acc, v0, a0);
        }
    } else {
        float m0 = -1e30f, m1 = -1e30f, m2 = -1e30f, m3 = -1e30f;
        float d0 = 0.f, d1 = 0.f, d2 = 0.f, d3 = 0.f;
        for (int j = j0 + lane; j < j1; j += 64) {
            int s = (int)csr[j].x;
            float4 as4 = *(const float4*)&als[s * 4];
            m0 = fmaxf(m0, lrelu(as4.x + ad.x));
            m1 = fmaxf(m1, lrelu(as4.y + ad.y));
            m2 = fmaxf(m2, lrelu(as4.z + ad.z));
            m3 = fmaxf(m3, lrelu(as4.w + ad.w));
        }
#pragma unroll
        for (int off = 32; off >= 1; off >>= 1) {
            m0 = fmaxf(m0, __shfl_xor(m0, off));
            m1 = fmaxf(m1, __shfl_xor(m1, off));
            m2 = fmaxf(m2, __shfl_xor(m2, off));
            m3 = fmaxf(m3, __shfl_xor(m3, off));
        }
        for (int j = j0 + lane; j < j1; j += 64) {
            int s = (int)csr[j].x;
            float4 as4 = *(const float4*)&als[s * 4];
            d0 += __expf(lrelu(as4.x + ad.x) - m0);
            d1 += __expf(lrelu(as4.y + ad.y) - m1);
            d2 += __expf(lrelu(as4.z + ad.z) - m2);
            d3 += __expf(lrelu(as4.w + ad.w) - m3);
        }
#pragma unroll
        for (int off = 32; off >= 1; off >>= 1) {
            d0 += __shfl_xor(d0, off);
            d1 += __shfl_xor(d1, off);
            d2 += __shfl_xor(d2, off);
            d3 += __shfl_xor(d3, off);
        }
        float mh   = h == 0 ? m0 : h == 1 ? m1 : h == 2 ? m2 : m3;
        float invh = 1.f / (h == 0 ? d0 : h == 1 ? d1 : h == 2 ? d2 : d3);
        float adh  = h == 0 ? ad.x : h == 1 ? ad.y : h == 2 ? ad.z : ad.w;
        for (int j = j0 + sub; j < j1; j += 2) {
            uint2 c0 = csr[j];
            float a0 = __expf(lrelu(als[c0.x * 4 + h] + adh) - mh) * invh;
            uint4 v0 = *(const uint4*)&hg[(size_t)c0.x * 256 + col];
            acc8(acc, v0, a0);
        }
    }

    // epilogue: fold sub-halves, bias+relu into LDS, block-level column partial -> ppart
#pragma unroll
    for (int i = 0; i < 8; ++i) acc[i] += __shfl_xor(acc[i], 32);
    if (lane < 32) {
#pragma unroll
        for (int i = 0; i < 8; ++i) srows[wv][col + i] = fmaxf(acc[i] + bg[col + i], 0.f);
    }
    __syncthreads();
    int t = threadIdx.x;
    ppart[(size_t)blockIdx.x * 256 + t] = srows[0][t] + srows[1][t] + srows[2][t] + srows[3][t];
}

// ---------------- reduce 12500 block partials -> 196 partials ----------------
__global__ __launch_bounds__(256) void reduce_kernel(const float* __restrict__ ppart, float* __restrict__ p2) {
    int t = threadIdx.x;
    int r0 = blockIdx.x * 64;
    int r1 = r0 + 64 < 12500 ? r0 + 64 : 12500;
    float s = 0.f;
    for (int r = r0; r < r1; ++r) s += ppart[(size_t)r * 256 + t];
    p2[blockIdx.x * 256 + t] = s;
}

__global__ __launch_bounds__(256) void mlp_kernel(const float* __restrict__ p2,
                                                  const float* __restrict__ Wc1, const float* __restrict__ bc1,
                                                  const float* __restrict__ Wc2, const float* __restrict__ bc2,
                                                  const float* __restrict__ Wc3, const float* __restrict__ bc3,
                                                  float* __restrict__ out) {
    __shared__ float p[256], z1[128], z2[64];
    int t = threadIdx.x;
    float s0 = 0.f;
    for (int b = 0; b < SCAN_B; ++b) s0 += p2[b * 256 + t];
    p[t] = s0 * (1.0f / NNODES);
    __syncthreads();
    if (t < 128) {
        float s = bc1[t];
        for (int k = 0; k < 256; ++k) s += p[k] * Wc1[k * 128 + t];
        z1[t] = fmaxf(s, 0.f);
    }
    __syncthreads();
    if (t < 64) {
        float s = bc2[t];
        for (int k = 0; k < 128; ++k) s += z1[k] * Wc2[k * 64 + t];
        z2[t] = fmaxf(s, 0.f);
    }
    __syncthreads();
    if (t < 8) {
        float s = bc3[t];
        for (int k = 0; k < 64; ++k) s += z2[k] * Wc3[k * 8 + t];
        out[t] = s;
    }
}

extern "C" void kernel_launch(void* const* d_in, const int* in_sizes, int n_in,
                              void* d_out, int out_size, void* d_ws, size_t ws_size,
                              hipStream_t stream) {
    const float* x   = (const float*)d_in[0];
    const int*   ei  = (const int*)d_in[1];
    const float* W1  = (const float*)d_in[2];  const float* b1  = (const float*)d_in[3];
    const float* W2  = (const float*)d_in[4];  const float* b2  = (const float*)d_in[5];
    const float* W3  = (const float*)d_in[6];  const float* b3  = (const float*)d_in[7];
    const float* Wg  = (const float*)d_in[8];
    const float* asr = (const float*)d_in[9];  const float* ads = (const float*)d_in[10];
    const float* bg  = (const float*)d_in[11];
    const float* Wc1 = (const float*)d_in[12]; const float* bc1 = (const float*)d_in[13];
    const float* Wc2 = (const float*)d_in[14]; const float* bc2 = (const float*)d_in[15];
    const float* Wc3 = (const float*)d_in[16]; const float* bc3 = (const float*)d_in[17];
    float* out = (float*)d_out;

    char* w = (char*)d_ws;
    float* deg    = (float*)w; w += (size_t)NNODES * 4;          // deg+cursor adjacent: one memset
    int*   cursor = (int*)w;   w += (size_t)NNODES * 4;
    float* dinv   = (float*)w; w += (size_t)NNODES * 4;
    int*   rowp   = (int*)w;   w += 200016;                      // (NNODES+1)*4 padded
    int*   bsum   = (int*)w;   w += 256 * 4;
    int*   bofs   = (int*)w;   w += 256 * 4;
    uint2* csr    = (uint2*)w; w += (size_t)EN * 8;
    float* als    = (float*)w; w += (size_t)NNODES * 4 * 4;
    float* ald    = (float*)w; w += (size_t)NNODES * 4 * 4;
    float* ppart  = (float*)w; w += (size_t)12500 * 256 * 4;
    float* p2     = (float*)w; w += (size_t)SCAN_B * 256 * 4;
    float* asp    = (float*)w; w += 4 * 128 * 4;
    float* adp    = (float*)w; w += 4 * 128 * 4;
    unsigned short* W1th = (unsigned short*)w; w += 128 * 256 * 2;
    unsigned short* W1tl = (unsigned short*)w; w += 128 * 256 * 2;
    unsigned short* W2th = (unsigned short*)w; w += 256 * 256 * 2;
    unsigned short* W2tl = (unsigned short*)w; w += 256 * 256 * 2;
    unsigned short* W3th = (unsigned short*)w; w += 256 * 128 * 2;
    unsigned short* W3tl = (unsigned short*)w; w += 256 * 128 * 2;
    unsigned short* Wgth = (unsigned short*)w; w += 128 * 256 * 2;
    unsigned short* Wgtl = (unsigned short*)w; w += 128 * 256 * 2;
    unsigned short* U1 = (unsigned short*)w; w += (size_t)NNODES * 256 * 2;
    unsigned short* U2 = (unsigned short*)w; w += (size_t)NNODES * 256 * 2;
    unsigned short* U3 = (unsigned short*)w; w += (size_t)NNODES * 256 * 2;
    unsigned short* U4 = (unsigned short*)w; w += (size_t)NNODES * 256 * 2;

    // prologue: one memset (deg+cursor contiguous), fused prep, 2-level scan, CSR scatter
    hipMemsetAsync(deg, 0, (size_t)NNODES * 8, stream);
    prep_kernel<<<3125, 256, 0, stream>>>(ei, deg, x, U1, W1, W2, W3, Wg, asr, ads,
                                          W1th, W1tl, W2th, W2tl, W3th, W3tl, Wgth, Wgtl, asp, adp);
    scan_part1<<<SCAN_B, 256, 0, stream>>>(deg, rowp, bsum, dinv);
    scan_part2<<<1, 256, 0, stream>>>(bsum, bofs, rowp);
    scatter_kernel<<<(EN + 255) / 256, 256, 0, stream>>>(ei, rowp, bofs, cursor, dinv, csr);

    dim3 gA((NNODES + 127) / 128, 2);   // Nc = 256
    dim3 gB((NNODES + 127) / 128, 1);   // Nc = 128
    int aggBlocks = (NNODES * 64 + 255) / 256;   // 12500

    // GCN 1 (reordered): aggX = agg(xbf) [N,128] -> U2; h1 = relu(aggX@W1 + b1) -> U3
    gcn_agg_bf<128, 0><<<aggBlocks, 256, 0, stream>>>(U1, rowp, bofs, csr, nullptr, nullptr,
                                                      nullptr, nullptr, nullptr, nullptr, U2);
    gemm_bf<1><<<gA, 256, 0, stream>>>(U2, W1th, W1tl, b1, U3, NNODES, 128, 256);

    // GCN 2: t2 = h1@W2 -> U1; h2 = relu(agg(t2) + b2) + h1 -> U2
    gemm_bf<0><<<gA, 256, 0, stream>>>(U3, W2th, W2tl, nullptr, U1, NNODES, 256, 256);
    gcn_agg_bf<256, 2><<<aggBlocks, 256, 0, stream>>>(U1, rowp, bofs, csr, b2, U3,
                                                      nullptr, nullptr, nullptr, nullptr, U2);

    // GCN 3: t3 = h2@W3 -> U4 [N,128]; h3 = relu(agg(t3) + b3) -> U1 + fused logits
    gemm_bf<0><<<gB, 256, 0, stream>>>(U2, W3th, W3tl, nullptr, U4, NNODES, 256, 128);
    gcn_agg_bf<128, 3><<<aggBlocks, 256, 0, stream>>>(U4, rowp, bofs, csr, b3, nullptr,
                                                      asp, adp, als, ald, U1);

    // GAT: hg = h3@Wg -> U2 [N,256]; softmax + gather + bias/relu + partial pool -> ppart
    gemm_bf<0><<<gA, 256, 0, stream>>>(U1, Wgth, Wgtl, nullptr, U2, NNODES, 128, 256);
    gat_pool<<<aggBlocks, 256, 0, stream>>>(U2, rowp, bofs, csr, als, ald, bg, ppart);

    // mean pool + MLP
    reduce_kernel<<<SCAN_B, 256, 0, stream>>>(ppart, p2);
    mlp_kernel<<<1, 256, 0, stream>>>(p2, Wc1, bc1, Wc2, bc2, Wc3, bc3, out);
}